// Round 13
// baseline (351.045 us; speedup 1.0000x reference)
//
#include <hip/hip_runtime.h>
#include <math.h>

typedef _Float16 h16;
typedef __attribute__((ext_vector_type(2))) _Float16 h16x2;
typedef __attribute__((ext_vector_type(4))) _Float16 h16x4;
typedef __attribute__((ext_vector_type(8))) _Float16 h16x8;
typedef __attribute__((ext_vector_type(4))) float f32x4;

#define NBATCH 2048
#define NT 64
#define KK 40
#define NL 7
#define SIGMA 0.02f
#define INVLN2 1.4426950408889634f

// LDS offsets in h16 units. All arrays XOR-swizzled: col ^= (row&7)<<3.
#define WT   0                     // W^T (wr,wi): [48 l][128 c=2n+ri]; dead after A
#define GRE  WT                    // overlay (phase B..C): G_re plane [48 l][64 m]
#define GIM  (WT + 48*64)          // overlay: G_im plane [48 l][64 m]
#define HCK  (WT + 48*128)         // H^H packed [40 k][128 c=2n+ri]
#define HNC  (HCK + 40*128)        // H interleaved [64 n][96 c=2k+ri pad 128]
#define B2T  (HNC + 64*128)        // S then S' [48 l][96 pad 128]; pads zeroed at init only
#define UOF  (B2T + 48*128)        // U [64 n][64 m] f16
#define LDSH (UOF + 64*64)         // 29696 h16 = 59392 B -> 2 blocks/CU

#define SWZ(row, c)  ((c) ^ (((row)&7)<<3))
#define MFMA16(a,b,c) __builtin_amdgcn_mfma_f32_16x16x32_f16((a),(b),(c),0,0,0)

static __device__ __forceinline__ float DOT2(h16x2 a, h16x2 b, float c) {
#if __has_builtin(__builtin_amdgcn_fdot2)
    return __builtin_amdgcn_fdot2(a, b, c, false);
#else
    return fmaf((float)a.x, (float)b.x, fmaf((float)a.y, (float)b.y, c));
#endif
}
static __device__ __forceinline__ h16x2 PK(float x, float y) {
    h16x2 r; r.x = (h16)x; r.y = (h16)y; return r;
}
// (wr,wi) -> (wi,-wr)
static __device__ __forceinline__ h16x2 SWNH(h16x2 w) {
    unsigned u = __builtin_bit_cast(unsigned, w);
    u = (u >> 16) | (u << 16);
    u ^= 0x80000000u;
    return __builtin_bit_cast(h16x2, u);
}
// per 32b word (sr',-si') -> (si',sr')
static __device__ __forceinline__ h16x8 imB(h16x8 v) {
    union { h16x8 h; unsigned u[4]; } x; x.h = v;
    #pragma unroll
    for (int i=0;i<4;++i){ unsigned t=x.u[i]; t=(t>>16)|(t<<16); x.u[i]=t^0x00008000u; }
    return x.h;
}
static __device__ __forceinline__ h16x2 GET8(h16x8 v, int i) {
    union { h16x8 w; h16x2 p[4]; } u; u.w = v; return u.p[i];
}

__global__ __launch_bounds__(256, 2) void gpnet_kernel(
    const float* __restrict__ gHr, const float* __restrict__ gHi,
    const float* __restrict__ gEta, const float* __restrict__ gU,
    const float* __restrict__ gB, float* __restrict__ gOut, int outFloats)
{
    __shared__ __align__(16) h16 sh[LDSH];
    __shared__ float sRed[4];

    const int tid = threadIdx.x;
    const int wv  = tid >> 6;      // wave 0..3
    const int ln  = tid & 63;
    const int col = ln & 15;       // fragment col / row component
    const int g   = ln >> 4;       // k-group

    const int bb = blockIdx.x;
    const float* hr = gHr + (size_t)bb * NT * KK;
    const float* hi = gHi + (size_t)bb * NT * KK;

    // ---- init: zero pads ONCE (no G overlay on B2T anymore -> stays clean)
    for (int i = tid; i < 512; i += 256)          // B2T rows 40..47 full width
        *(h16x2*)(sh + B2T + 40*128 + 2*i) = PK(0.f, 0.f);
    for (int e = tid; e < 320; e += 256) {        // B2T rows 0..39 pad cols 80..95
        int l = e >> 3, c = 80 + 2*(e & 7);
        *(h16x2*)(sh + B2T + l*128 + SWZ(l, c)) = PK(0.f, 0.f);
    }
    for (int i = tid; i < 512; i += 256) {        // HNC pad cols [80,96)
        int n = i >> 3, c = 80 + 2*(i & 7);
        *(h16x2*)(sh + HNC + n*128 + SWZ(n, c)) = PK(0.f, 0.f);
    }
    // H data (both layouts) + W^T = b0  (layer-0 collapse: W1 = b[0], Wi = 0)
    for (int i = tid; i < NT*KK; i += 256) {
        int n = i / KK, k = i % KK;
        float xr = hr[i], xi = hi[i];
        h16x2 p = PK(xr, xi);
        *(h16x2*)(sh + HCK + k*128 + SWZ(k, 2*n)) = p;
        *(h16x2*)(sh + HNC + n*128 + SWZ(n, 2*k)) = p;
        *(h16x2*)(sh + WT  + k*128 + SWZ(k, 2*n)) = PK(gB[i], 0.f);
    }
    // W-cache (f32 regs) = b0 at owned positions; power
    float Wr[3][4], Wi[3][4];
    float ps = 0.f;
    #pragma unroll
    for (int ct = 0; ct < 3; ++ct)
        #pragma unroll
        for (int r = 0; r < 4; ++r) {
            int n = 16*wv + 4*g + r, l = col + 16*ct;
            float b0 = (l < KK) ? gB[n*KK + l] : 0.f;
            Wr[ct][r] = b0; Wi[ct][r] = 0.f;
            ps += b0 * b0;
        }
    #pragma unroll
    for (int off = 32; off; off >>= 1) ps += __shfl_down(ps, off, 64);
    if (ln == 0) sRed[wv] = ps;
    __syncthreads();

    for (int t = 1; t < NL; ++t) {
        const float pw   = sRed[0] + sRed[1] + sRed[2] + sRed[3];
        const float cpen = 0.04f * (pw - 1.0f);
        const float etat = gEta[t];

        // b[t] prefetch at owned positions (used in phase C)
        float breg[3][4];
        #pragma unroll
        for (int ct = 0; ct < 3; ++ct)
            #pragma unroll
            for (int r = 0; r < 4; ++r) {
                int n = 16*wv + 4*g + r, l = col + 16*ct;
                breg[ct][r] = (l < KK) ? gB[(size_t)t*NT*KK + n*KK + l] : 0.f;
            }

        // ---- PHASE A (scalar dot2, 200 thr, 4k x 2l) || U-stage (56 thr)
        if (tid < 200) {
            const int k0 = (tid / 20) * 4;
            const int l0 = (tid % 20) * 2;
            float ar[4][2] = {}, ai[4][2] = {};
            #pragma unroll 4
            for (int c = 0; c < 16; ++c) {
                h16x8 w0 = *(const h16x8*)(sh + WT + (l0  )*128 + SWZ(l0,   c*8));
                h16x8 w1 = *(const h16x8*)(sh + WT + (l0+1)*128 + SWZ(l0+1, c*8));
                #pragma unroll
                for (int i = 0; i < 4; ++i) {
                    h16x8 hv = *(const h16x8*)(sh + HCK + (k0+i)*128 + SWZ(k0+i, c*8));
                    #pragma unroll
                    for (int wd = 0; wd < 4; ++wd) {
                        h16x2 hp  = GET8(hv, wd);
                        h16x2 wp0 = GET8(w0, wd), wp1 = GET8(w1, wd);
                        ar[i][0] = DOT2(wp0, hp, ar[i][0]);        // Re
                        ai[i][0] = DOT2(SWNH(wp0), hp, ai[i][0]);  // Im
                        ar[i][1] = DOT2(wp1, hp, ar[i][1]);
                        ai[i][1] = DOT2(SWNH(wp1), hp, ai[i][1]);
                    }
                }
            }
            // UNSCALED S^T: (sr, si) at row l, col 2k
            #pragma unroll
            for (int i = 0; i < 4; ++i)
                #pragma unroll
                for (int j = 0; j < 2; ++j)
                    *(h16x2*)(sh + B2T + (l0+j)*128 + SWZ(l0+j, 2*(k0+i))) =
                        PK(ar[i][j], ai[i][j]);
        } else {
            // threads 200..255: stage U[t] -> LDS (coalesced j*56+td order)
            const float2* u2 = (const float2*)(gU + (size_t)t * NT * NT);
            const int td = tid - 200;
            #pragma unroll 4
            for (int j = 0; j < 37; ++j) {
                int e2 = j*56 + td;
                if (e2 < 2048) {
                    float2 v = u2[e2];
                    int n = e2 >> 5, m2 = (e2 & 31) * 2;
                    *(h16x2*)(sh + UOF + n*64 + SWZ(n, m2)) = PK(v.x, v.y);
                }
            }
        }
        __syncthreads();                       // (1) unscaled S + U ready

        // ---- coefficients: 4 lanes per user k; scale column k of S^T
        if (tid < 160) {
            const int k = tid >> 2, q = tid & 3;
            h16x2 va[10];
            #pragma unroll
            for (int ii = 0; ii < 10; ++ii)
                va[ii] = *(const h16x2*)(sh + B2T + (q*10+ii)*128 + SWZ(q*10+ii, 2*k));
            float rs = 0.f, dd = 0.f;
            #pragma unroll
            for (int ii = 0; ii < 10; ++ii) rs = DOT2(va[ii], va[ii], rs);
            const int dk = k - q*10;
            if (dk >= 0 && dk < 10) dd = DOT2(va[dk], va[dk], 0.f);
            rs += __shfl_xor(rs, 1, 64); rs += __shfl_xor(rs, 2, 64);
            dd += __shfl_xor(dd, 1, 64); dd += __shfl_xor(dd, 2, 64);
            float T  = rs + SIGMA, Is = rs - dd + SIGMA;
            float cA_ = 2.f * INVLN2 / T;
            float cC_ = -2.f * INVLN2 * dd / (Is * T);
            #pragma unroll
            for (int ii = 0; ii < 10; ++ii) {
                int l = q*10 + ii;
                float c = (l == k) ? cA_ : cC_;
                *(h16x2*)(sh + B2T + l*128 + SWZ(l, 2*k)) =
                    PK((float)va[ii].x * c, -(float)va[ii].y * c);   // (sr',-si')
            }
        }
        __syncthreads();                       // (2) S' ready; WT now dead

        // ---- PHASE B (MFMA): G[n][l]; G written straight to WT-region planes
        f32x4 gRe[3], gIm[3];
        #pragma unroll
        for (int ct = 0; ct < 3; ++ct) { gRe[ct] = (f32x4){0.f,0.f,0.f,0.f}; gIm[ct] = (f32x4){0.f,0.f,0.f,0.f}; }
        {
            const int nrow = col + 16*wv;
            #pragma unroll
            for (int q = 0; q < 3; ++q) {
                h16x8 af = *(const h16x8*)(sh + HNC + nrow*128 + SWZ(nrow, g*8 + 32*q));
                #pragma unroll
                for (int ct = 0; ct < 3; ++ct) {
                    int lr = col + 16*ct;
                    h16x8 bf = *(const h16x8*)(sh + B2T + lr*128 + SWZ(lr, g*8 + 32*q));
                    gRe[ct] = MFMA16(af, bf, gRe[ct]);
                    gIm[ct] = MFMA16(af, imB(bf), gIm[ct]);
                }
            }
        }
        {
            const int n0w = 16*wv + 4*g;
            #pragma unroll
            for (int ct = 0; ct < 3; ++ct) {
                int l = col + 16*ct;
                h16x4 g4, q4;
                #pragma unroll
                for (int r = 0; r < 4; ++r) {
                    float vre = gRe[ct][r] - cpen * Wr[ct][r];
                    float vim = gIm[ct][r] - cpen * Wi[ct][r];
                    g4[r] = (h16)vre; q4[r] = (h16)vim;
                }
                *(h16x4*)(sh + GRE + l*64 + SWZ(l, n0w)) = g4;
                *(h16x4*)(sh + GIM + l*64 + SWZ(l, n0w)) = q4;
            }
        }
        __syncthreads();                       // (3) G planes visible

        // ---- PHASE C (MFMA): Ug = U x G
        f32x4 cRe[3], cIm[3];
        #pragma unroll
        for (int ct = 0; ct < 3; ++ct) { cRe[ct] = (f32x4){0.f,0.f,0.f,0.f}; cIm[ct] = (f32x4){0.f,0.f,0.f,0.f}; }
        {
            const int nrow = col + 16*wv;
            #pragma unroll
            for (int q = 0; q < 2; ++q) {
                h16x8 af = *(const h16x8*)(sh + UOF + nrow*64 + SWZ(nrow, g*8 + 32*q));
                #pragma unroll
                for (int ct = 0; ct < 3; ++ct) {
                    const int l = col + 16*ct;
                    h16x8 fre = *(const h16x8*)(sh + GRE + l*64 + SWZ(l, g*8 + 32*q));
                    h16x8 fim = *(const h16x8*)(sh + GIM + l*64 + SWZ(l, g*8 + 32*q));
                    cRe[ct] = MFMA16(af, fre, cRe[ct]);
                    cIm[ct] = MFMA16(af, fim, cIm[ct]);
                }
            }
        }
        __syncthreads();                       // (4) all G reads done; WT writable

        // ---- W update (regs) + packed W^T store + power fold
        float ps2 = 0.f;
        {
            const int n0w = 16*wv + 4*g;
            #pragma unroll
            for (int ct = 0; ct < 3; ++ct) {
                int l = col + 16*ct;
                h16x8 wvv;
                #pragma unroll
                for (int r = 0; r < 4; ++r) {
                    float ur = cRe[ct][r], ui = cIm[ct][r];
                    float wr = Wr[ct][r] - etat*(ur - ui) + breg[ct][r];
                    float wi = Wi[ct][r] - etat*(ui + ur);
                    Wr[ct][r] = wr; Wi[ct][r] = wi;
                    wvv[2*r]   = (h16)wr;
                    wvv[2*r+1] = (h16)wi;
                    if (l < KK) ps2 += wr*wr + wi*wi;
                }
                if (l < KK)
                    *(h16x8*)(sh + WT + l*128 + SWZ(l, 2*n0w)) = wvv;
            }
        }
        #pragma unroll
        for (int off = 32; off; off >>= 1) ps2 += __shfl_down(ps2, off, 64);
        if (ln == 0) sRed[wv] = ps2;
        __syncthreads();                       // (5) Wt + sRed ready
    }

    // ---- final normalization from registers
    const float pwf   = sRed[0] + sRed[1] + sRed[2] + sRed[3];
    const float scale = 1.0f / (sqrtf(pwf) + 1e-6f);

    if (outFloats >= 2 * NBATCH * NT * KK) {
        float2* ob = (float2*)(gOut + (size_t)bb * NT * KK * 2);
        #pragma unroll
        for (int ct = 0; ct < 3; ++ct)
            #pragma unroll
            for (int r = 0; r < 4; ++r) {
                int n = 16*wv + 4*g + r, l = col + 16*ct;
                if (l < KK) {
                    float2 v; v.x = Wr[ct][r]*scale; v.y = Wi[ct][r]*scale;
                    ob[n*KK + l] = v;
                }
            }
    } else {
        float* ob = gOut + (size_t)bb * NT * KK;
        #pragma unroll
        for (int ct = 0; ct < 3; ++ct)
            #pragma unroll
            for (int r = 0; r < 4; ++r) {
                int n = 16*wv + 4*g + r, l = col + 16*ct;
                if (l < KK) ob[n*KK + l] = Wr[ct][r] * scale;
            }
    }
}

extern "C" void kernel_launch(void* const* d_in, const int* in_sizes, int n_in,
                              void* d_out, int out_size, void* d_ws, size_t ws_size,
                              hipStream_t stream) {
    (void)in_sizes; (void)n_in; (void)d_ws; (void)ws_size;
    const float* Hr  = (const float*)d_in[0];
    const float* Hi  = (const float*)d_in[1];
    const float* eta = (const float*)d_in[2];
    const float* U   = (const float*)d_in[3];
    const float* b   = (const float*)d_in[4];
    float* out = (float*)d_out;
    gpnet_kernel<<<NBATCH, 256, 0, stream>>>(Hr, Hi, eta, U, b, out, out_size);
}

// Round 14
// 254.133 us; speedup vs baseline: 1.3813x; 1.3813x over previous
//
#include <hip/hip_runtime.h>
#include <math.h>

typedef _Float16 h16;
typedef __attribute__((ext_vector_type(2))) _Float16 h16x2;
typedef __attribute__((ext_vector_type(4))) _Float16 h16x4;
typedef __attribute__((ext_vector_type(8))) _Float16 h16x8;
typedef __attribute__((ext_vector_type(4))) float f32x4;

#define NBATCH 2048
#define NT 64
#define KK 40
#define NL 7
#define SIGMA 0.02f
#define INVLN2 1.4426950408889634f

// LDS offsets in h16 units. Row stride 128 h16 (256 B) except U/G-planes (64).
// WT/HCK: SWZW (c ^ (row&15)<<3).  HNC/B2T/G/U: SWZ (c ^ (row&7)<<3).
#define WT   0                    // W^T packed (wr,wi): [48 l][128 c=2n+ri]
#define HCK  (48*128)             // H^H packed: [48 k][128 c=2n+ri] (hr,hi)
#define HNC  (HCK + 48*128)       // H interleaved: [64 n][96 c=2k+ri pad 128]
#define B2T  (HNC + 64*128)       // S then S' packed [48 l][96 c=2k+ri]
#define GRE  B2T                  // overlay after barrier: G_re plane [48 l][64 m]
#define GIM  (B2T + 48*64)        // overlay: G_im plane [48 l][64 m]
#define UOF  (B2T + 48*128)       // U [64 n][64 m] f16
#define LDSH (UOF + 64*64)        // 30720 h16 = 61440 B -> 2 blocks/CU

#define SWZ(row, c)  ((c) ^ (((row)&7)<<3))
#define SWZW(row, c) ((c) ^ (((row)&15)<<3))
#define MFMA16(a,b,c) __builtin_amdgcn_mfma_f32_16x16x32_f16((a),(b),(c),0,0,0)

static __device__ __forceinline__ float DOT2(h16x2 a, h16x2 b, float c) {
#if __has_builtin(__builtin_amdgcn_fdot2)
    return __builtin_amdgcn_fdot2(a, b, c, false);
#else
    return fmaf((float)a.x, (float)b.x, fmaf((float)a.y, (float)b.y, c));
#endif
}
static __device__ __forceinline__ h16x2 PK(float x, float y) {
    h16x2 r; r.x = (h16)x; r.y = (h16)y; return r;
}
// (wr,wi) -> (wi,-wr)
static __device__ __forceinline__ h16x2 SWNH(h16x2 w) {
    unsigned u = __builtin_bit_cast(unsigned, w);
    u = (u >> 16) | (u << 16);
    u ^= 0x80000000u;
    return __builtin_bit_cast(h16x2, u);
}
// per 32b word (sr',-si') -> (si',sr')
static __device__ __forceinline__ h16x8 imB(h16x8 v) {
    union { h16x8 h; unsigned u[4]; } x; x.h = v;
    #pragma unroll
    for (int i=0;i<4;++i){ unsigned t=x.u[i]; t=(t>>16)|(t<<16); x.u[i]=t^0x00008000u; }
    return x.h;
}
static __device__ __forceinline__ h16x2 GET8(h16x8 v, int i) {
    union { h16x8 w; h16x2 p[4]; } u; u.w = v; return u.p[i];
}

__global__ __launch_bounds__(256, 2) void gpnet_kernel(
    const float* __restrict__ gHr, const float* __restrict__ gHi,
    const float* __restrict__ gEta, const float* __restrict__ gU,
    const float* __restrict__ gB, float* __restrict__ gOut, int outFloats)
{
    __shared__ __align__(16) h16 sh[LDSH];
    __shared__ float sRed[4];

    const int tid = threadIdx.x;
    const int wv  = tid >> 6;      // wave 0..3
    const int ln  = tid & 63;
    const int col = ln & 15;       // fragment col / row component
    const int g   = ln >> 4;       // k-group

    const int bb = blockIdx.x;
    const float* hr = gHr + (size_t)bb * NT * KK;
    const float* hi = gHi + (size_t)bb * NT * KK;

    // ---- init: zero pads (uniform zeros -> raw stores are swizzle-safe)
    for (int i = tid; i < 512; i += 256) {
        *(h16x2*)(sh + WT  + 40*128 + 2*i) = PK(0.f, 0.f);   // Wt rows 40..47
        *(h16x2*)(sh + HCK + 40*128 + 2*i) = PK(0.f, 0.f);   // Hck rows 40..47
    }
    for (int i = tid; i < 512; i += 256) {                   // Hnc logical cols [80,96)
        int n = i >> 3, c = 80 + 2*(i & 7);
        *(h16x2*)(sh + HNC + n*128 + SWZ(n, c)) = PK(0.f, 0.f);
    }
    // H data (both layouts) + W^T = b0  (layer-0 collapse: W1 = b[0], Wi = 0)
    for (int i = tid; i < NT*KK; i += 256) {
        int n = i / KK, k = i % KK;
        float xr = hr[i], xi = hi[i];
        h16x2 p = PK(xr, xi);
        *(h16x2*)(sh + HCK + k*128 + SWZW(k, 2*n)) = p;
        *(h16x2*)(sh + HNC + n*128 + SWZ(n, 2*k)) = p;
        *(h16x2*)(sh + WT  + k*128 + SWZW(k, 2*n)) = PK(gB[i], 0.f);
    }
    // W-cache (f32 regs) = b0 at owned positions; power
    float Wr[3][4], Wi[3][4];
    float ps = 0.f;
    #pragma unroll
    for (int ct = 0; ct < 3; ++ct)
        #pragma unroll
        for (int r = 0; r < 4; ++r) {
            int n = 16*wv + 4*g + r, l = col + 16*ct;
            float b0 = (l < KK) ? gB[n*KK + l] : 0.f;
            Wr[ct][r] = b0; Wi[ct][r] = 0.f;
            ps += b0 * b0;
        }
    #pragma unroll
    for (int off = 32; off; off >>= 1) ps += __shfl_down(ps, off, 64);
    if (ln == 0) sRed[wv] = ps;
    __syncthreads();

    for (int t = 1; t < NL; ++t) {
        const float pw   = sRed[0] + sRed[1] + sRed[2] + sRed[3];
        const float cpen = 0.04f * (pw - 1.0f);
        const float etat = gEta[t];

        // early global loads: U[t] pairs and b[t] at owned positions
        float2 ureg[8];
        {
            const float2* u2 = (const float2*)(gU + (size_t)t * NT * NT);
            #pragma unroll
            for (int j = 0; j < 8; ++j) ureg[j] = u2[tid + j*256];
        }
        float breg[3][4];
        #pragma unroll
        for (int ct = 0; ct < 3; ++ct)
            #pragma unroll
            for (int r = 0; r < 4; ++r) {
                int n = 16*wv + 4*g + r, l = col + 16*ct;
                breg[ct][r] = (l < KK) ? gB[(size_t)t*NT*KK + n*KK + l] : 0.f;
            }

        // ---- pad-zero B2T (G overlay dirtied it last layer; B reads it as S')
        for (int e = tid; e < 704; e += 256) {
            int l, k;
            if (e < 384) { l = 40 + e / 48; k = e % 48; }
            else { int f = e - 384; l = f >> 3; k = 40 + (f & 7); }
            *(h16x2*)(sh + B2T + l*128 + SWZ(l, 2*k)) = PK(0.f, 0.f);
        }

        // ---- PHASE A (scalar dot2, 200 thr, 4k x 2l tiles)
        if (tid < 200) {
            const int k0 = (tid / 20) * 4;
            const int l0 = (tid % 20) * 2;
            float ar[4][2] = {}, ai[4][2] = {};
            #pragma unroll 4
            for (int c = 0; c < 16; ++c) {
                h16x8 w0 = *(const h16x8*)(sh + WT + (l0  )*128 + SWZW(l0,   c*8));
                h16x8 w1 = *(const h16x8*)(sh + WT + (l0+1)*128 + SWZW(l0+1, c*8));
                #pragma unroll
                for (int i = 0; i < 4; ++i) {
                    h16x8 hv = *(const h16x8*)(sh + HCK + (k0+i)*128 + SWZW(k0+i, c*8));
                    #pragma unroll
                    for (int wd = 0; wd < 4; ++wd) {
                        h16x2 hp  = GET8(hv, wd);
                        h16x2 wp0 = GET8(w0, wd), wp1 = GET8(w1, wd);
                        ar[i][0] = DOT2(wp0, hp, ar[i][0]);        // Re
                        ai[i][0] = DOT2(SWNH(wp0), hp, ai[i][0]);  // Im
                        ar[i][1] = DOT2(wp1, hp, ar[i][1]);
                        ai[i][1] = DOT2(SWNH(wp1), hp, ai[i][1]);
                    }
                }
            }
            // packed UNSCALED S^T writes: row l0+j, cols 2k0..2k0+7
            #pragma unroll
            for (int j = 0; j < 2; ++j) {
                h16x8 sv;
                #pragma unroll
                for (int i = 0; i < 4; ++i) {
                    sv[2*i]   = (h16)ar[i][j];
                    sv[2*i+1] = (h16)ai[i][j];
                }
                *(h16x8*)(sh + B2T + (l0+j)*128 + SWZ(l0+j, 2*k0)) = sv;
            }
        }
        __syncthreads();                       // (1) unscaled S ready

        // ---- coefficients: 4 lanes per user k; scale column k of S^T
        if (tid < 160) {
            const int k = tid >> 2, q = tid & 3;
            h16x2 va[10];
            #pragma unroll
            for (int ii = 0; ii < 10; ++ii)
                va[ii] = *(const h16x2*)(sh + B2T + (q*10+ii)*128 + SWZ(q*10+ii, 2*k));
            float rs = 0.f, dd = 0.f;
            #pragma unroll
            for (int ii = 0; ii < 10; ++ii) rs = DOT2(va[ii], va[ii], rs);
            const int dk = k - q*10;
            if (dk >= 0 && dk < 10) dd = DOT2(va[dk], va[dk], 0.f);
            rs += __shfl_xor(rs, 1, 64); rs += __shfl_xor(rs, 2, 64);
            dd += __shfl_xor(dd, 1, 64); dd += __shfl_xor(dd, 2, 64);
            float T  = rs + SIGMA, Is = rs - dd + SIGMA;
            float cA_ = 2.f * INVLN2 / T;
            float cC_ = -2.f * INVLN2 * dd / (Is * T);
            #pragma unroll
            for (int ii = 0; ii < 10; ++ii) {
                int l = q*10 + ii;
                float c = (l == k) ? cA_ : cC_;
                *(h16x2*)(sh + B2T + l*128 + SWZ(l, 2*k)) =
                    PK((float)va[ii].x * c, -(float)va[ii].y * c);   // (sr',-si')
            }
        }
        __syncthreads();                       // (2) S' ready

        // ---- PHASE B (MFMA): G[n][l], row-strip n in [16wv,16wv+16)
        f32x4 gRe[3], gIm[3];
        #pragma unroll
        for (int ct = 0; ct < 3; ++ct) { gRe[ct] = (f32x4){0.f,0.f,0.f,0.f}; gIm[ct] = (f32x4){0.f,0.f,0.f,0.f}; }
        {
            const int nrow = col + 16*wv;
            #pragma unroll
            for (int q = 0; q < 3; ++q) {
                h16x8 af = *(const h16x8*)(sh + HNC + nrow*128 + SWZ(nrow, g*8 + 32*q));
                #pragma unroll
                for (int ct = 0; ct < 3; ++ct) {
                    int lr = col + 16*ct;
                    h16x8 bf = *(const h16x8*)(sh + B2T + lr*128 + SWZ(lr, g*8 + 32*q));
                    gRe[ct] = MFMA16(af, bf, gRe[ct]);
                    gIm[ct] = MFMA16(af, imB(bf), gIm[ct]);
                }
            }
        }
        // U[t] -> LDS (disjoint region; read by phase C after barrier 4)
        #pragma unroll
        for (int j = 0; j < 8; ++j) {
            int e2 = tid + j*256;
            int n = e2 >> 5, m2 = (e2 & 31) * 2;
            *(h16x2*)(sh + UOF + n*64 + SWZ(n, m2)) = PK(ureg[j].x, ureg[j].y);
        }
        __syncthreads();                       // (3) all B2t reads done
        // write G as split planes (packed h16x4); penalty folded into the pack
        {
            const int n0w = 16*wv + 4*g;
            #pragma unroll
            for (int ct = 0; ct < 3; ++ct) {
                int l = col + 16*ct;
                h16x4 g4, q4;
                #pragma unroll
                for (int r = 0; r < 4; ++r) {
                    g4[r] = (h16)(gRe[ct][r] - cpen * Wr[ct][r]);
                    q4[r] = (h16)(gIm[ct][r] - cpen * Wi[ct][r]);
                }
                *(h16x4*)(sh + GRE + l*64 + SWZ(l, n0w)) = g4;
                *(h16x4*)(sh + GIM + l*64 + SWZ(l, n0w)) = q4;
            }
        }
        __syncthreads();                       // (4) G planes + U visible

        // ---- PHASE C (MFMA): Ug = U x G ; W update; power fold
        f32x4 cRe[3], cIm[3];
        #pragma unroll
        for (int ct = 0; ct < 3; ++ct) { cRe[ct] = (f32x4){0.f,0.f,0.f,0.f}; cIm[ct] = (f32x4){0.f,0.f,0.f,0.f}; }
        {
            const int nrow = col + 16*wv;
            #pragma unroll
            for (int q = 0; q < 2; ++q) {
                h16x8 af = *(const h16x8*)(sh + UOF + nrow*64 + SWZ(nrow, g*8 + 32*q));
                #pragma unroll
                for (int ct = 0; ct < 3; ++ct) {
                    const int l = col + 16*ct;
                    h16x8 fre = *(const h16x8*)(sh + GRE + l*64 + SWZ(l, g*8 + 32*q));
                    h16x8 fim = *(const h16x8*)(sh + GIM + l*64 + SWZ(l, g*8 + 32*q));
                    cRe[ct] = MFMA16(af, fre, cRe[ct]);
                    cIm[ct] = MFMA16(af, fim, cIm[ct]);
                }
            }
        }
        float ps2 = 0.f;
        {
            const int n0w = 16*wv + 4*g;
            #pragma unroll
            for (int ct = 0; ct < 3; ++ct) {
                int l = col + 16*ct;
                h16x8 wvv;
                #pragma unroll
                for (int r = 0; r < 4; ++r) {
                    float ur = cRe[ct][r], ui = cIm[ct][r];
                    float wr = Wr[ct][r] - etat*(ur - ui) + breg[ct][r];
                    float wi = Wi[ct][r] - etat*(ui + ur);
                    Wr[ct][r] = wr; Wi[ct][r] = wi;
                    wvv[2*r]   = (h16)wr;
                    wvv[2*r+1] = (h16)wi;
                    if (l < KK) ps2 += wr*wr + wi*wi;
                }
                if (l < KK)
                    *(h16x8*)(sh + WT + l*128 + SWZW(l, 2*n0w)) = wvv;
            }
        }
        #pragma unroll
        for (int off = 32; off; off >>= 1) ps2 += __shfl_down(ps2, off, 64);
        if (ln == 0) sRed[wv] = ps2;
        __syncthreads();                       // (5) Wt + sRed ready
    }

    // ---- final normalization from registers
    const float pwf   = sRed[0] + sRed[1] + sRed[2] + sRed[3];
    const float scale = 1.0f / (sqrtf(pwf) + 1e-6f);

    if (outFloats >= 2 * NBATCH * NT * KK) {
        float2* ob = (float2*)(gOut + (size_t)bb * NT * KK * 2);
        #pragma unroll
        for (int ct = 0; ct < 3; ++ct)
            #pragma unroll
            for (int r = 0; r < 4; ++r) {
                int n = 16*wv + 4*g + r, l = col + 16*ct;
                if (l < KK) {
                    float2 v; v.x = Wr[ct][r]*scale; v.y = Wi[ct][r]*scale;
                    ob[n*KK + l] = v;
                }
            }
    } else {
        float* ob = gOut + (size_t)bb * NT * KK;
        #pragma unroll
        for (int ct = 0; ct < 3; ++ct)
            #pragma unroll
            for (int r = 0; r < 4; ++r) {
                int n = 16*wv + 4*g + r, l = col + 16*ct;
                if (l < KK) ob[n*KK + l] = Wr[ct][r] * scale;
            }
    }
}

extern "C" void kernel_launch(void* const* d_in, const int* in_sizes, int n_in,
                              void* d_out, int out_size, void* d_ws, size_t ws_size,
                              hipStream_t stream) {
    (void)in_sizes; (void)n_in; (void)d_ws; (void)ws_size;
    const float* Hr  = (const float*)d_in[0];
    const float* Hi  = (const float*)d_in[1];
    const float* eta = (const float*)d_in[2];
    const float* U   = (const float*)d_in[3];
    const float* b   = (const float*)d_in[4];
    float* out = (float*)d_out;
    gpnet_kernel<<<NBATCH, 256, 0, stream>>>(Hr, Hi, eta, U, b, out, out_size);
}

// Round 15
// 116.910 us; speedup vs baseline: 3.0027x; 2.1737x over previous
//
#include <hip/hip_runtime.h>
#include <math.h>

typedef _Float16 h16;
typedef __attribute__((ext_vector_type(2))) _Float16 h16x2;
typedef __attribute__((ext_vector_type(4))) _Float16 h16x4;
typedef __attribute__((ext_vector_type(8))) _Float16 h16x8;
typedef __attribute__((ext_vector_type(4))) float f32x4;

#define NBATCH 2048
#define NT 64
#define KK 40
#define NL 7
#define SIGMA 0.02f
#define INVLN2 1.4426950408889634f

// LDS offsets in h16 units. Row stride 128 h16 (256 B) except U/G-planes (64).
// WT/HCK: SWZW (c ^ (row&15)<<3).  HNC/B2T/G/U: SWZ (c ^ (row&7)<<3).
#define WT   0                    // W^T packed (wr,wi): [48 l][128 c=2n+ri]
#define HCK  (48*128)             // H^H packed: [48 k][128 c=2n+ri] (hr,hi)
#define HNC  (HCK + 48*128)       // H interleaved: [64 n][96 c=2k+ri pad 128]
#define B2T  (HNC + 64*128)       // S then S' packed [48 l][96 c=2k+ri]
#define GRE  B2T                  // overlay after barrier: G_re plane [48 l][64 m]
#define GIM  (B2T + 48*64)        // overlay: G_im plane [48 l][64 m]
#define UOF  (B2T + 48*128)       // U [64 n][64 m] f16
#define LDSH (UOF + 64*64)        // 30720 h16 = 61440 B -> 2 blocks/CU

#define SWZ(row, c)  ((c) ^ (((row)&7)<<3))
#define SWZW(row, c) ((c) ^ (((row)&15)<<3))
#define MFMA16(a,b,c) __builtin_amdgcn_mfma_f32_16x16x32_f16((a),(b),(c),0,0,0)

static __device__ __forceinline__ float DOT2(h16x2 a, h16x2 b, float c) {
#if __has_builtin(__builtin_amdgcn_fdot2)
    return __builtin_amdgcn_fdot2(a, b, c, false);
#else
    return fmaf((float)a.x, (float)b.x, fmaf((float)a.y, (float)b.y, c));
#endif
}
static __device__ __forceinline__ h16x2 PK(float x, float y) {
    h16x2 r; r.x = (h16)x; r.y = (h16)y; return r;
}
// per 32b word (wr,wi) -> (wi,-wr)
static __device__ __forceinline__ h16x8 conjA(h16x8 v) {
    union { h16x8 h; unsigned u[4]; } x; x.h = v;
    #pragma unroll
    for (int i=0;i<4;++i){ unsigned t=x.u[i]; t=(t>>16)|(t<<16); x.u[i]=t^0x80000000u; }
    return x.h;
}
// per 32b word (sr',-si') -> (si',sr')
static __device__ __forceinline__ h16x8 imB(h16x8 v) {
    union { h16x8 h; unsigned u[4]; } x; x.h = v;
    #pragma unroll
    for (int i=0;i<4;++i){ unsigned t=x.u[i]; t=(t>>16)|(t<<16); x.u[i]=t^0x00008000u; }
    return x.h;
}

__global__ __launch_bounds__(256, 2) void gpnet_kernel(
    const float* __restrict__ gHr, const float* __restrict__ gHi,
    const float* __restrict__ gEta, const float* __restrict__ gU,
    const float* __restrict__ gB, float* __restrict__ gOut, int outFloats)
{
    __shared__ __align__(16) h16 sh[LDSH];
    __shared__ float sRed[4];

    const int tid = threadIdx.x;
    const int wv  = tid >> 6;      // wave 0..3
    const int ln  = tid & 63;
    const int col = ln & 15;       // fragment col / row component
    const int g   = ln >> 4;       // k-group

    const int bb = blockIdx.x;
    const float* hr = gHr + (size_t)bb * NT * KK;
    const float* hi = gHi + (size_t)bb * NT * KK;

    // ---- init: zero pads (uniform zeros -> raw stores are swizzle-safe)
    for (int i = tid; i < 512; i += 256) {
        *(h16x2*)(sh + WT  + 40*128 + 2*i) = PK(0.f, 0.f);   // Wt rows 40..47
        *(h16x2*)(sh + HCK + 40*128 + 2*i) = PK(0.f, 0.f);   // Hck rows 40..47
    }
    for (int i = tid; i < 512; i += 256) {                   // Hnc logical cols [80,96)
        int n = i >> 3, c = 80 + 2*(i & 7);
        *(h16x2*)(sh + HNC + n*128 + SWZ(n, c)) = PK(0.f, 0.f);
    }
    // H data (both layouts) + W^T = b0  (layer-0 collapse: W1 = b[0], Wi = 0)
    for (int i = tid; i < NT*KK; i += 256) {
        int n = i / KK, k = i % KK;
        float xr = hr[i], xi = hi[i];
        h16x2 p = PK(xr, xi);
        *(h16x2*)(sh + HCK + k*128 + SWZW(k, 2*n)) = p;
        *(h16x2*)(sh + HNC + n*128 + SWZ(n, 2*k)) = p;
        *(h16x2*)(sh + WT  + k*128 + SWZW(k, 2*n)) = PK(gB[i], 0.f);
    }
    // W-cache (f32 regs) = b0 at owned positions; power
    float Wr[3][4], Wi[3][4];
    float ps = 0.f;
    #pragma unroll
    for (int ct = 0; ct < 3; ++ct)
        #pragma unroll
        for (int r = 0; r < 4; ++r) {
            int n = 16*wv + 4*g + r, l = col + 16*ct;
            float b0 = (l < KK) ? gB[n*KK + l] : 0.f;
            Wr[ct][r] = b0; Wi[ct][r] = 0.f;
            ps += b0 * b0;
        }
    #pragma unroll
    for (int off = 32; off; off >>= 1) ps += __shfl_down(ps, off, 64);
    if (ln == 0) sRed[wv] = ps;
    __syncthreads();

    for (int t = 1; t < NL; ++t) {
        const float pw   = sRed[0] + sRed[1] + sRed[2] + sRed[3];
        const float cpen = 0.04f * (pw - 1.0f);
        const float etat = gEta[t];

        // early global loads: U[t] pairs and b[t] at owned positions
        float2 ureg[8];
        {
            const float2* u2 = (const float2*)(gU + (size_t)t * NT * NT);
            #pragma unroll
            for (int j = 0; j < 8; ++j) ureg[j] = u2[tid + j*256];
        }
        float breg[3][4];
        #pragma unroll
        for (int ct = 0; ct < 3; ++ct)
            #pragma unroll
            for (int r = 0; r < 4; ++r) {
                int n = 16*wv + 4*g + r, l = col + 16*ct;
                breg[ct][r] = (l < KK) ? gB[(size_t)t*NT*KK + n*KK + l] : 0.f;
            }

        // ---- PHASE A (MFMA, waves 0..2): UNSCALED S^T -> B2T.
        // S^T[l][k] = sum_n conj(H[n,k]) W[n,l]; K-dim c = 2n+ri (128 h16).
        // Writes cover ALL l in [0,48) x k in [0,48): rows/cols >=40 are zero
        // because WT/HCK pad rows are zero -> no per-layer pad-rezero needed.
        if (wv < 3) {
            f32x4 aRe[3], aIm[3];
            #pragma unroll
            for (int rt = 0; rt < 3; ++rt) { aRe[rt] = (f32x4){0.f,0.f,0.f,0.f}; aIm[rt] = (f32x4){0.f,0.f,0.f,0.f}; }
            const int kcol = col + 16*wv;
            #pragma unroll
            for (int q = 0; q < 4; ++q) {
                h16x8 bf = *(const h16x8*)(sh + HCK + kcol*128 + SWZW(kcol, g*8 + 32*q));
                #pragma unroll
                for (int rt = 0; rt < 3; ++rt) {
                    int lrow = col + 16*rt;
                    h16x8 af = *(const h16x8*)(sh + WT + lrow*128 + SWZW(lrow, g*8 + 32*q));
                    aRe[rt] = MFMA16(af, bf, aRe[rt]);        // Re: (wr,wi).(hr,hi)
                    aIm[rt] = MFMA16(conjA(af), bf, aIm[rt]); // Im: (wi,-wr).(hr,hi)
                }
            }
            // write UNSCALED (sr, si) at row l, col 2*kcol  (same layout the
            // proven scalar phase A produced)
            #pragma unroll
            for (int rt = 0; rt < 3; ++rt)
                #pragma unroll
                for (int r = 0; r < 4; ++r) {
                    int l = 16*rt + 4*g + r;
                    *(h16x2*)(sh + B2T + l*128 + SWZ(l, 2*kcol)) =
                        PK(aRe[rt][r], aIm[rt][r]);
                }
        }
        __syncthreads();                       // (1) unscaled S ready

        // ---- coefficients (PROVEN scalar pass): 4 lanes per user k
        if (tid < 160) {
            const int k = tid >> 2, q = tid & 3;
            h16x2 va[10];
            #pragma unroll
            for (int ii = 0; ii < 10; ++ii)
                va[ii] = *(const h16x2*)(sh + B2T + (q*10+ii)*128 + SWZ(q*10+ii, 2*k));
            float rs = 0.f, dd = 0.f;
            #pragma unroll
            for (int ii = 0; ii < 10; ++ii) rs = DOT2(va[ii], va[ii], rs);
            const int dk = k - q*10;
            if (dk >= 0 && dk < 10) dd = DOT2(va[dk], va[dk], 0.f);
            rs += __shfl_xor(rs, 1, 64); rs += __shfl_xor(rs, 2, 64);
            dd += __shfl_xor(dd, 1, 64); dd += __shfl_xor(dd, 2, 64);
            float T  = rs + SIGMA, Is = rs - dd + SIGMA;
            float cA_ = 2.f * INVLN2 / T;
            float cC_ = -2.f * INVLN2 * dd / (Is * T);
            #pragma unroll
            for (int ii = 0; ii < 10; ++ii) {
                int l = q*10 + ii;
                float c = (l == k) ? cA_ : cC_;
                *(h16x2*)(sh + B2T + l*128 + SWZ(l, 2*k)) =
                    PK((float)va[ii].x * c, -(float)va[ii].y * c);   // (sr',-si')
            }
        }
        __syncthreads();                       // (2) S' ready

        // ---- PHASE B (MFMA): G[n][l], row-strip n in [16wv,16wv+16)
        f32x4 gRe[3], gIm[3];
        #pragma unroll
        for (int ct = 0; ct < 3; ++ct) { gRe[ct] = (f32x4){0.f,0.f,0.f,0.f}; gIm[ct] = (f32x4){0.f,0.f,0.f,0.f}; }
        {
            const int nrow = col + 16*wv;
            #pragma unroll
            for (int q = 0; q < 3; ++q) {
                h16x8 af = *(const h16x8*)(sh + HNC + nrow*128 + SWZ(nrow, g*8 + 32*q));
                #pragma unroll
                for (int ct = 0; ct < 3; ++ct) {
                    int lr = col + 16*ct;
                    h16x8 bf = *(const h16x8*)(sh + B2T + lr*128 + SWZ(lr, g*8 + 32*q));
                    gRe[ct] = MFMA16(af, bf, gRe[ct]);
                    gIm[ct] = MFMA16(af, imB(bf), gIm[ct]);
                }
            }
        }
        // U[t] -> LDS (disjoint region; read by phase C after barrier 4)
        #pragma unroll
        for (int j = 0; j < 8; ++j) {
            int e2 = tid + j*256;
            int n = e2 >> 5, m2 = (e2 & 31) * 2;
            *(h16x2*)(sh + UOF + n*64 + SWZ(n, m2)) = PK(ureg[j].x, ureg[j].y);
        }
        __syncthreads();                       // (3) all B2t reads done
        // write G as split planes (packed h16x4); penalty folded into the pack
        {
            const int n0w = 16*wv + 4*g;
            #pragma unroll
            for (int ct = 0; ct < 3; ++ct) {
                int l = col + 16*ct;
                h16x4 g4, q4;
                #pragma unroll
                for (int r = 0; r < 4; ++r) {
                    g4[r] = (h16)(gRe[ct][r] - cpen * Wr[ct][r]);
                    q4[r] = (h16)(gIm[ct][r] - cpen * Wi[ct][r]);
                }
                *(h16x4*)(sh + GRE + l*64 + SWZ(l, n0w)) = g4;
                *(h16x4*)(sh + GIM + l*64 + SWZ(l, n0w)) = q4;
            }
        }
        __syncthreads();                       // (4) G planes + U visible

        // ---- PHASE C (MFMA): Ug = U x G ; W update; power fold
        f32x4 cRe[3], cIm[3];
        #pragma unroll
        for (int ct = 0; ct < 3; ++ct) { cRe[ct] = (f32x4){0.f,0.f,0.f,0.f}; cIm[ct] = (f32x4){0.f,0.f,0.f,0.f}; }
        {
            const int nrow = col + 16*wv;
            #pragma unroll
            for (int q = 0; q < 2; ++q) {
                h16x8 af = *(const h16x8*)(sh + UOF + nrow*64 + SWZ(nrow, g*8 + 32*q));
                #pragma unroll
                for (int ct = 0; ct < 3; ++ct) {
                    const int l = col + 16*ct;
                    h16x8 fre = *(const h16x8*)(sh + GRE + l*64 + SWZ(l, g*8 + 32*q));
                    h16x8 fim = *(const h16x8*)(sh + GIM + l*64 + SWZ(l, g*8 + 32*q));
                    cRe[ct] = MFMA16(af, fre, cRe[ct]);
                    cIm[ct] = MFMA16(af, fim, cIm[ct]);
                }
            }
        }
        float ps2 = 0.f;
        {
            const int n0w = 16*wv + 4*g;
            #pragma unroll
            for (int ct = 0; ct < 3; ++ct) {
                int l = col + 16*ct;
                h16x8 wvv;
                #pragma unroll
                for (int r = 0; r < 4; ++r) {
                    float ur = cRe[ct][r], ui = cIm[ct][r];
                    float wr = Wr[ct][r] - etat*(ur - ui) + breg[ct][r];
                    float wi = Wi[ct][r] - etat*(ui + ur);
                    Wr[ct][r] = wr; Wi[ct][r] = wi;
                    wvv[2*r]   = (h16)wr;
                    wvv[2*r+1] = (h16)wi;
                    if (l < KK) ps2 += wr*wr + wi*wi;
                }
                if (l < KK)
                    *(h16x8*)(sh + WT + l*128 + SWZW(l, 2*n0w)) = wvv;
            }
        }
        #pragma unroll
        for (int off = 32; off; off >>= 1) ps2 += __shfl_down(ps2, off, 64);
        if (ln == 0) sRed[wv] = ps2;
        __syncthreads();                       // (5) Wt + sRed ready
    }

    // ---- final normalization from registers
    const float pwf   = sRed[0] + sRed[1] + sRed[2] + sRed[3];
    const float scale = 1.0f / (sqrtf(pwf) + 1e-6f);

    if (outFloats >= 2 * NBATCH * NT * KK) {
        float2* ob = (float2*)(gOut + (size_t)bb * NT * KK * 2);
        #pragma unroll
        for (int ct = 0; ct < 3; ++ct)
            #pragma unroll
            for (int r = 0; r < 4; ++r) {
                int n = 16*wv + 4*g + r, l = col + 16*ct;
                if (l < KK) {
                    float2 v; v.x = Wr[ct][r]*scale; v.y = Wi[ct][r]*scale;
                    ob[n*KK + l] = v;
                }
            }
    } else {
        float* ob = gOut + (size_t)bb * NT * KK;
        #pragma unroll
        for (int ct = 0; ct < 3; ++ct)
            #pragma unroll
            for (int r = 0; r < 4; ++r) {
                int n = 16*wv + 4*g + r, l = col + 16*ct;
                if (l < KK) ob[n*KK + l] = Wr[ct][r] * scale;
            }
    }
}

extern "C" void kernel_launch(void* const* d_in, const int* in_sizes, int n_in,
                              void* d_out, int out_size, void* d_ws, size_t ws_size,
                              hipStream_t stream) {
    (void)in_sizes; (void)n_in; (void)d_ws; (void)ws_size;
    const float* Hr  = (const float*)d_in[0];
    const float* Hi  = (const float*)d_in[1];
    const float* eta = (const float*)d_in[2];
    const float* U   = (const float*)d_in[3];
    const float* b   = (const float*)d_in[4];
    float* out = (float*)d_out;
    gpnet_kernel<<<NBATCH, 256, 0, stream>>>(Hr, Hi, eta, U, b, out, out_size);
}

// Round 16
// 114.248 us; speedup vs baseline: 3.0727x; 1.0233x over previous
//
#include <hip/hip_runtime.h>
#include <math.h>

typedef _Float16 h16;
typedef __attribute__((ext_vector_type(2))) _Float16 h16x2;
typedef __attribute__((ext_vector_type(4))) _Float16 h16x4;
typedef __attribute__((ext_vector_type(8))) _Float16 h16x8;
typedef __attribute__((ext_vector_type(4))) float f32x4;

#define NBATCH 2048
#define NT 64
#define KK 40
#define NL 7
#define SIGMA 0.02f
#define INVLN2 1.4426950408889634f

// LDS (h16 units). Two rotating [48][128] regions RA/RB swap roles per layer:
//   P-role: W^T (SWZW) at layer start; G planes (SWZ) after phase B.
//   Q-role: S/S' (SWZ) during A..B; W^T_next (SWZW) after phase C.
#define RA   0
#define RB   (48*128)
#define HCK  (2*48*128)           // H^H packed [48 k][128 c=2n+ri], SWZW
#define HNC  (HCK + 48*128)       // H interleaved [64 n][96 c=2k+ri pad 128], SWZ
#define UOF  (HNC + 64*128)       // U [64 n][64 m] f16, SWZ
#define LDSH (UOF + 64*64)        // 30720 h16 = 61440 B -> 2 blocks/CU

#define SWZ(row, c)  ((c) ^ (((row)&7)<<3))
#define SWZW(row, c) ((c) ^ (((row)&15)<<3))
#define MFMA16(a,b,c) __builtin_amdgcn_mfma_f32_16x16x32_f16((a),(b),(c),0,0,0)

static __device__ __forceinline__ float DOT2(h16x2 a, h16x2 b, float c) {
#if __has_builtin(__builtin_amdgcn_fdot2)
    return __builtin_amdgcn_fdot2(a, b, c, false);
#else
    return fmaf((float)a.x, (float)b.x, fmaf((float)a.y, (float)b.y, c));
#endif
}
static __device__ __forceinline__ h16x2 PK(float x, float y) {
    h16x2 r; r.x = (h16)x; r.y = (h16)y; return r;
}
// per 32b word (wr,wi) -> (wi,-wr)
static __device__ __forceinline__ h16x8 conjA(h16x8 v) {
    union { h16x8 h; unsigned u[4]; } x; x.h = v;
    #pragma unroll
    for (int i=0;i<4;++i){ unsigned t=x.u[i]; t=(t>>16)|(t<<16); x.u[i]=t^0x80000000u; }
    return x.h;
}
// per 32b word (sr',-si') -> (si',sr')
static __device__ __forceinline__ h16x8 imB(h16x8 v) {
    union { h16x8 h; unsigned u[4]; } x; x.h = v;
    #pragma unroll
    for (int i=0;i<4;++i){ unsigned t=x.u[i]; t=(t>>16)|(t<<16); x.u[i]=t^0x00008000u; }
    return x.h;
}

__global__ __launch_bounds__(256, 2) void gpnet_kernel(
    const float* __restrict__ gHr, const float* __restrict__ gHi,
    const float* __restrict__ gEta, const float* __restrict__ gU,
    const float* __restrict__ gB, float* __restrict__ gOut, int outFloats)
{
    __shared__ __align__(16) h16 sh[LDSH];
    __shared__ float sRed[4];

    const int tid = threadIdx.x;
    const int wv  = tid >> 6;      // wave 0..3
    const int ln  = tid & 63;
    const int col = ln & 15;       // fragment col / row component
    const int g   = ln >> 4;       // k-group

    const int bb = blockIdx.x;
    const float* hr = gHr + (size_t)bb * NT * KK;
    const float* hi = gHi + (size_t)bb * NT * KK;

    // ---- init: zero pads (uniform zeros -> raw stores are swizzle-safe)
    for (int i = tid; i < 512; i += 256) {
        *(h16x2*)(sh + RA  + 40*128 + 2*i) = PK(0.f, 0.f);   // W^T rows 40..47
        *(h16x2*)(sh + HCK + 40*128 + 2*i) = PK(0.f, 0.f);   // Hck rows 40..47
    }
    for (int i = tid; i < 512; i += 256) {                   // Hnc logical cols [80,96)
        int n = i >> 3, c = 80 + 2*(i & 7);
        *(h16x2*)(sh + HNC + n*128 + SWZ(n, c)) = PK(0.f, 0.f);
    }
    // H data (both layouts) + W^T = b0 into RA (layer-0 collapse: W1 = b[0])
    for (int i = tid; i < NT*KK; i += 256) {
        int n = i / KK, k = i % KK;
        float xr = hr[i], xi = hi[i];
        h16x2 p = PK(xr, xi);
        *(h16x2*)(sh + HCK + k*128 + SWZW(k, 2*n)) = p;
        *(h16x2*)(sh + HNC + n*128 + SWZ(n, 2*k)) = p;
        *(h16x2*)(sh + RA  + k*128 + SWZW(k, 2*n)) = PK(gB[i], 0.f);
    }
    // W-cache (f32 regs) = b0 at owned positions; power
    float Wr[3][4], Wi[3][4];
    float ps = 0.f;
    #pragma unroll
    for (int ct = 0; ct < 3; ++ct)
        #pragma unroll
        for (int r = 0; r < 4; ++r) {
            int n = 16*wv + 4*g + r, l = col + 16*ct;
            float b0 = (l < KK) ? gB[n*KK + l] : 0.f;
            Wr[ct][r] = b0; Wi[ct][r] = 0.f;
            ps += b0 * b0;
        }
    #pragma unroll
    for (int off = 32; off; off >>= 1) ps += __shfl_down(ps, off, 64);
    if (ln == 0) sRed[wv] = ps;
    __syncthreads();

    for (int t = 1; t < NL; ++t) {
        const int P = (t & 1) ? RA : RB;   // W^T at layer start; G planes later
        const int Q = (t & 1) ? RB : RA;   // S/S'; W^T_next after C
        const int GREo = P, GIMo = P + 48*64;

        const float pw   = sRed[0] + sRed[1] + sRed[2] + sRed[3];
        const float cpen = 0.04f * (pw - 1.0f);
        const float etat = gEta[t];

        // b[t] prefetch at owned positions (used in phase C)
        float breg[3][4];
        #pragma unroll
        for (int ct = 0; ct < 3; ++ct)
            #pragma unroll
            for (int r = 0; r < 4; ++r) {
                int n = 16*wv + 4*g + r, l = col + 16*ct;
                breg[ct][r] = (l < KK) ? gB[(size_t)t*NT*KK + n*KK + l] : 0.f;
            }

        // ---- PHASE A (MFMA, waves 0..2): UNSCALED S^T -> Q. Wave 3: stage U.
        if (wv < 3) {
            f32x4 aRe[3], aIm[3];
            #pragma unroll
            for (int rt = 0; rt < 3; ++rt) { aRe[rt] = (f32x4){0.f,0.f,0.f,0.f}; aIm[rt] = (f32x4){0.f,0.f,0.f,0.f}; }
            const int kcol = col + 16*wv;
            #pragma unroll
            for (int q = 0; q < 4; ++q) {
                h16x8 bf = *(const h16x8*)(sh + HCK + kcol*128 + SWZW(kcol, g*8 + 32*q));
                #pragma unroll
                for (int rt = 0; rt < 3; ++rt) {
                    int lrow = col + 16*rt;
                    h16x8 af = *(const h16x8*)(sh + P + lrow*128 + SWZW(lrow, g*8 + 32*q));
                    aRe[rt] = MFMA16(af, bf, aRe[rt]);        // Re: (wr,wi).(hr,hi)
                    aIm[rt] = MFMA16(conjA(af), bf, aIm[rt]); // Im: (wi,-wr).(hr,hi)
                }
            }
            #pragma unroll
            for (int rt = 0; rt < 3; ++rt)
                #pragma unroll
                for (int r = 0; r < 4; ++r) {
                    int l = 16*rt + 4*g + r;
                    *(h16x2*)(sh + Q + l*128 + SWZ(l, 2*kcol)) =
                        PK(aRe[rt][r], aIm[rt][r]);
                }
        } else {
            // wave 3: U[t] -> UOF (read by phase C; visible from barrier 1)
            const float2* u2 = (const float2*)(gU + (size_t)t * NT * NT);
            #pragma unroll 8
            for (int j = 0; j < 32; ++j) {
                int e2 = j*64 + ln;
                float2 v = u2[e2];
                int n = e2 >> 5, m2 = (e2 & 31) * 2;
                *(h16x2*)(sh + UOF + n*64 + SWZ(n, m2)) = PK(v.x, v.y);
            }
        }
        __syncthreads();                       // (1) S in Q + U visible

        // ---- coefficients (proven scalar pass): 4 lanes per user k
        if (tid < 160) {
            const int k = tid >> 2, q = tid & 3;
            h16x2 va[10];
            #pragma unroll
            for (int ii = 0; ii < 10; ++ii)
                va[ii] = *(const h16x2*)(sh + Q + (q*10+ii)*128 + SWZ(q*10+ii, 2*k));
            float rs = 0.f, dd = 0.f;
            #pragma unroll
            for (int ii = 0; ii < 10; ++ii) rs = DOT2(va[ii], va[ii], rs);
            const int dk = k - q*10;
            if (dk >= 0 && dk < 10) dd = DOT2(va[dk], va[dk], 0.f);
            rs += __shfl_xor(rs, 1, 64); rs += __shfl_xor(rs, 2, 64);
            dd += __shfl_xor(dd, 1, 64); dd += __shfl_xor(dd, 2, 64);
            float T  = rs + SIGMA, Is = rs - dd + SIGMA;
            float cA_ = 2.f * INVLN2 / T;
            float cC_ = -2.f * INVLN2 * dd / (Is * T);
            #pragma unroll
            for (int ii = 0; ii < 10; ++ii) {
                int l = q*10 + ii;
                float c = (l == k) ? cA_ : cC_;
                *(h16x2*)(sh + Q + l*128 + SWZ(l, 2*k)) =
                    PK((float)va[ii].x * c, -(float)va[ii].y * c);   // (sr',-si')
            }
        }
        __syncthreads();                       // (2) S' ready; P (old W^T) dead

        // ---- PHASE B (MFMA): G[n][l]; writes G planes straight into P
        f32x4 gRe[3], gIm[3];
        #pragma unroll
        for (int ct = 0; ct < 3; ++ct) { gRe[ct] = (f32x4){0.f,0.f,0.f,0.f}; gIm[ct] = (f32x4){0.f,0.f,0.f,0.f}; }
        {
            const int nrow = col + 16*wv;
            #pragma unroll
            for (int q = 0; q < 3; ++q) {
                h16x8 af = *(const h16x8*)(sh + HNC + nrow*128 + SWZ(nrow, g*8 + 32*q));
                #pragma unroll
                for (int ct = 0; ct < 3; ++ct) {
                    int lr = col + 16*ct;
                    h16x8 bf = *(const h16x8*)(sh + Q + lr*128 + SWZ(lr, g*8 + 32*q));
                    gRe[ct] = MFMA16(af, bf, gRe[ct]);
                    gIm[ct] = MFMA16(af, imB(bf), gIm[ct]);
                }
            }
        }
        {
            const int n0w = 16*wv + 4*g;
            #pragma unroll
            for (int ct = 0; ct < 3; ++ct) {
                int l = col + 16*ct;
                h16x4 g4, q4;
                #pragma unroll
                for (int r = 0; r < 4; ++r) {
                    g4[r] = (h16)(gRe[ct][r] - cpen * Wr[ct][r]);
                    q4[r] = (h16)(gIm[ct][r] - cpen * Wi[ct][r]);
                }
                *(h16x4*)(sh + GREo + l*64 + SWZ(l, n0w)) = g4;
                *(h16x4*)(sh + GIMo + l*64 + SWZ(l, n0w)) = q4;
            }
        }
        __syncthreads();                       // (3) G planes visible; Q dead

        // ---- PHASE C (MFMA): Ug = U x G ; W update; W^T_next -> Q
        f32x4 cRe[3], cIm[3];
        #pragma unroll
        for (int ct = 0; ct < 3; ++ct) { cRe[ct] = (f32x4){0.f,0.f,0.f,0.f}; cIm[ct] = (f32x4){0.f,0.f,0.f,0.f}; }
        {
            const int nrow = col + 16*wv;
            #pragma unroll
            for (int q = 0; q < 2; ++q) {
                h16x8 af = *(const h16x8*)(sh + UOF + nrow*64 + SWZ(nrow, g*8 + 32*q));
                #pragma unroll
                for (int ct = 0; ct < 3; ++ct) {
                    const int l = col + 16*ct;
                    h16x8 fre = *(const h16x8*)(sh + GREo + l*64 + SWZ(l, g*8 + 32*q));
                    h16x8 fim = *(const h16x8*)(sh + GIMo + l*64 + SWZ(l, g*8 + 32*q));
                    cRe[ct] = MFMA16(af, fre, cRe[ct]);
                    cIm[ct] = MFMA16(af, fim, cIm[ct]);
                }
            }
        }
        float ps2 = 0.f;
        {
            const int n0w = 16*wv + 4*g;
            #pragma unroll
            for (int ct = 0; ct < 3; ++ct) {
                int l = col + 16*ct;
                h16x8 wvv;
                #pragma unroll
                for (int r = 0; r < 4; ++r) {
                    float ur = cRe[ct][r], ui = cIm[ct][r];
                    float wr = Wr[ct][r] - etat*(ur - ui) + breg[ct][r];
                    float wi = Wi[ct][r] - etat*(ui + ur);
                    Wr[ct][r] = wr; Wi[ct][r] = wi;
                    wvv[2*r]   = (h16)wr;
                    wvv[2*r+1] = (h16)wi;
                    if (l < KK) ps2 += wr*wr + wi*wi;
                }
                if (l < KK)
                    *(h16x8*)(sh + Q + l*128 + SWZW(l, 2*n0w)) = wvv;
            }
            // zero W^T pad rows 40..47 of Q (next layer's A reads them)
            h16x4 z4; z4[0] = (h16)0.f; z4[1] = (h16)0.f; z4[2] = (h16)0.f; z4[3] = (h16)0.f;
            *(h16x4*)(sh + Q + 40*128 + 4*tid) = z4;
        }
        #pragma unroll
        for (int off = 32; off; off >>= 1) ps2 += __shfl_down(ps2, off, 64);
        if (ln == 0) sRed[wv] = ps2;
        __syncthreads();                       // (4) layer end
    }

    // ---- final normalization from registers
    const float pwf   = sRed[0] + sRed[1] + sRed[2] + sRed[3];
    const float scale = 1.0f / (sqrtf(pwf) + 1e-6f);

    if (outFloats >= 2 * NBATCH * NT * KK) {
        float2* ob = (float2*)(gOut + (size_t)bb * NT * KK * 2);
        #pragma unroll
        for (int ct = 0; ct < 3; ++ct)
            #pragma unroll
            for (int r = 0; r < 4; ++r) {
                int n = 16*wv + 4*g + r, l = col + 16*ct;
                if (l < KK) {
                    float2 v; v.x = Wr[ct][r]*scale; v.y = Wi[ct][r]*scale;
                    ob[n*KK + l] = v;
                }
            }
    } else {
        float* ob = gOut + (size_t)bb * NT * KK;
        #pragma unroll
        for (int ct = 0; ct < 3; ++ct)
            #pragma unroll
            for (int r = 0; r < 4; ++r) {
                int n = 16*wv + 4*g + r, l = col + 16*ct;
                if (l < KK) ob[n*KK + l] = Wr[ct][r] * scale;
            }
    }
}

extern "C" void kernel_launch(void* const* d_in, const int* in_sizes, int n_in,
                              void* d_out, int out_size, void* d_ws, size_t ws_size,
                              hipStream_t stream) {
    (void)in_sizes; (void)n_in; (void)d_ws; (void)ws_size;
    const float* Hr  = (const float*)d_in[0];
    const float* Hi  = (const float*)d_in[1];
    const float* eta = (const float*)d_in[2];
    const float* U   = (const float*)d_in[3];
    const float* b   = (const float*)d_in[4];
    float* out = (float*)d_out;
    gpnet_kernel<<<NBATCH, 256, 0, stream>>>(Hr, Hi, eta, U, b, out, out_size);
}